// Round 2
// baseline (4113.528 us; speedup 1.0000x reference)
//
#include <hip/hip_runtime.h>
#include <hip/hip_bf16.h>

#define D_MODEL 1024
#define NUM_HEADS 16
#define D_K 64
#define S_LEN 2048
#define BATCH 4

typedef unsigned short u16;

__device__ __forceinline__ float bf2f(u16 u) {
    union { unsigned int i; float f; } v; v.i = ((unsigned int)u) << 16; return v.f;
}
__device__ __forceinline__ u16 f2bf(float f) {
    union { unsigned int i; float f; } v; v.f = f;
    unsigned int x = v.i;
    return (u16)((x + 0x7FFFu + ((x >> 16) & 1u)) >> 16); // round-nearest-even
}

// C[M,N] = A[M,K] @ W[K,N] + bias[N].
// A: fp32 or bf16 (TA), W/bias: fp32, C: fp32 or bf16 (TC). fp32 accumulate.
// 128x64 tile, BK=16, 256 threads, 8x4 per thread.
template <typename TA, typename TC>
__global__ __launch_bounds__(256) void gemm_bias(
    const TA* __restrict__ A, const float* __restrict__ W,
    const float* __restrict__ bias, TC* __restrict__ C,
    int M, int K, int N)
{
    __shared__ float As[16][132];   // [k][m], padded: row base 132*4B = 16B-aligned
    __shared__ float Bs[16][68];    // [k][n]

    const int tid = threadIdx.x;
    const int tx = tid & 15;        // col group: cols tx*4..+3
    const int ty = tid >> 4;        // row group: rows ty*8..+7
    const int m0 = blockIdx.y * 128;
    const int n0 = blockIdx.x * 64;

    float acc[8][4] = {};

    for (int k0 = 0; k0 < K; k0 += 16) {
        // stage A tile: 128 rows x 16 k = 512 vec4 segments, 2 per thread
        #pragma unroll
        for (int f = tid; f < 512; f += 256) {
            const int row = f >> 2;
            const int kq  = (f & 3) * 4;
            const TA* ap = A + (size_t)(m0 + row) * K + k0 + kq;
            float v0, v1, v2, v3;
            if constexpr (sizeof(TA) == 4) {
                float4 t = *reinterpret_cast<const float4*>(ap);
                v0 = t.x; v1 = t.y; v2 = t.z; v3 = t.w;
            } else {
                ushort4 t = *reinterpret_cast<const ushort4*>(ap);
                v0 = bf2f(t.x); v1 = bf2f(t.y); v2 = bf2f(t.z); v3 = bf2f(t.w);
            }
            As[kq + 0][row] = v0;
            As[kq + 1][row] = v1;
            As[kq + 2][row] = v2;
            As[kq + 3][row] = v3;
        }
        // stage B tile: 16 k x 64 n = 256 vec4, 1 per thread
        {
            const int krow = tid >> 4;
            const int nq   = (tid & 15) * 4;
            float4 t = *reinterpret_cast<const float4*>(
                W + (size_t)(k0 + krow) * N + n0 + nq);
            Bs[krow][nq + 0] = t.x;
            Bs[krow][nq + 1] = t.y;
            Bs[krow][nq + 2] = t.z;
            Bs[krow][nq + 3] = t.w;
        }
        __syncthreads();

        #pragma unroll
        for (int kk = 0; kk < 16; ++kk) {
            float ar[8], br[4];
            #pragma unroll
            for (int i = 0; i < 8; ++i) ar[i] = As[kk][ty * 8 + i];
            #pragma unroll
            for (int j = 0; j < 4; ++j) br[j] = Bs[kk][tx * 4 + j];
            #pragma unroll
            for (int i = 0; i < 8; ++i)
                #pragma unroll
                for (int j = 0; j < 4; ++j)
                    acc[i][j] = fmaf(ar[i], br[j], acc[i][j]);
        }
        __syncthreads();
    }

    float bc[4];
    #pragma unroll
    for (int j = 0; j < 4; ++j) bc[j] = bias[n0 + tx * 4 + j];

    #pragma unroll
    for (int i = 0; i < 8; ++i) {
        const int mrow = m0 + ty * 8 + i;
        if constexpr (sizeof(TC) == 4) {
            float4 ov;
            ov.x = acc[i][0] + bc[0];
            ov.y = acc[i][1] + bc[1];
            ov.z = acc[i][2] + bc[2];
            ov.w = acc[i][3] + bc[3];
            *reinterpret_cast<float4*>(&C[(size_t)mrow * N + n0 + tx * 4]) = ov;
        } else {
            ushort4 ov;
            ov.x = f2bf(acc[i][0] + bc[0]);
            ov.y = f2bf(acc[i][1] + bc[1]);
            ov.z = f2bf(acc[i][2] + bc[2]);
            ov.w = f2bf(acc[i][3] + bc[3]);
            *reinterpret_cast<ushort4*>(&C[(size_t)mrow * N + n0 + tx * 4]) = ov;
        }
    }
}

// One wave64 per query row, 4 keys per iteration.
// lane = kg*16 + (dq/4): kg = key subgroup (0..3), dq = dim quad (0..60 step 4).
// Q/K/V bf16 [B,S,D_MODEL]; head h = columns h*64..h*64+63. Causal via loop bound.
__global__ __launch_bounds__(256) void attn_kernel(
    const u16* __restrict__ Q, const u16* __restrict__ K,
    const u16* __restrict__ V, u16* __restrict__ O)
{
    const int wave = threadIdx.x >> 6;
    const int lane = threadIdx.x & 63;
    const int kg = lane >> 4;
    const int dq = (lane & 15) * 4;

    const long row = (long)blockIdx.x * 4 + wave;     // 0 .. B*H*S-1
    const int q  = (int)(row & (S_LEN - 1));
    const int bh = (int)(row >> 11);
    const int h  = bh & (NUM_HEADS - 1);
    const int b  = bh >> 4;

    const size_t rowbase = ((size_t)b * S_LEN + q) * D_MODEL + h * D_K;
    const size_t kvbase  = (size_t)b * S_LEN * D_MODEL + h * D_K;

    ushort4 q4 = *reinterpret_cast<const ushort4*>(Q + rowbase + dq);
    const float scale = 0.125f;
    float qv0 = bf2f(q4.x) * scale, qv1 = bf2f(q4.y) * scale;
    float qv2 = bf2f(q4.z) * scale, qv3 = bf2f(q4.w) * scale;

    float m = -1e30f, l = 0.f;
    float o0 = 0.f, o1 = 0.f, o2 = 0.f, o3 = 0.f;

    for (int j0 = 0; j0 <= q; j0 += 4) {
        const int j = j0 + kg;   // may overshoot q by <=3: masked below, read stays in ws
        const size_t koff = kvbase + (size_t)j * D_MODEL + dq;
        ushort4 kv = *reinterpret_cast<const ushort4*>(K + koff);
        float s = qv0 * bf2f(kv.x) + qv1 * bf2f(kv.y)
                + qv2 * bf2f(kv.z) + qv3 * bf2f(kv.w);
        s += __shfl_xor(s, 1);
        s += __shfl_xor(s, 2);
        s += __shfl_xor(s, 4);
        s += __shfl_xor(s, 8);       // 16-lane group now holds score of key j0+kg
        if (j > q) s = -1e30f;       // causal tail mask
        float s1 = __shfl_xor(s, 16);
        float s2 = __shfl_xor(s, 32);
        float s3 = __shfl_xor(s1, 32);
        float mx = fmaxf(fmaxf(s, s1), fmaxf(s2, s3));
        if (mx > m + 8.f) {          // defer-max: rescale rarely (uniform branch)
            float co = __expf(m - mx);
            l *= co;
            o0 *= co; o1 *= co; o2 *= co; o3 *= co;
            m = mx;
        }
        float p  = __expf(s  - m);
        float p1 = __expf(s1 - m);
        float p2 = __expf(s2 - m);
        float p3 = __expf(s3 - m);
        l += p + p1 + p2 + p3;       // identical in every lane
        ushort4 vv = *reinterpret_cast<const ushort4*>(V + koff);
        o0 = fmaf(p, bf2f(vv.x), o0);
        o1 = fmaf(p, bf2f(vv.y), o1);
        o2 = fmaf(p, bf2f(vv.z), o2);
        o3 = fmaf(p, bf2f(vv.w), o3);
    }

    // sum o across the 4 key subgroups
    o0 += __shfl_xor(o0, 16); o0 += __shfl_xor(o0, 32);
    o1 += __shfl_xor(o1, 16); o1 += __shfl_xor(o1, 32);
    o2 += __shfl_xor(o2, 16); o2 += __shfl_xor(o2, 32);
    o3 += __shfl_xor(o3, 16); o3 += __shfl_xor(o3, 32);

    if (kg == 0) {
        const float inv = 1.f / l;
        ushort4 ov;
        ov.x = f2bf(o0 * inv);
        ov.y = f2bf(o1 * inv);
        ov.z = f2bf(o2 * inv);
        ov.w = f2bf(o3 * inv);
        *reinterpret_cast<ushort4*>(O + rowbase + dq) = ov;
    }
}

extern "C" void kernel_launch(void* const* d_in, const int* in_sizes, int n_in,
                              void* d_out, int out_size, void* d_ws, size_t ws_size,
                              hipStream_t stream) {
    const float* x  = (const float*)d_in[0];
    // d_in[1] = causal mask: applied structurally via loop bound — not read.
    const float* Wq = (const float*)d_in[2];
    const float* bq = (const float*)d_in[3];
    const float* Wk = (const float*)d_in[4];
    const float* bk = (const float*)d_in[5];
    const float* Wv = (const float*)d_in[6];
    const float* bv = (const float*)d_in[7];
    const float* Wo = (const float*)d_in[8];
    const float* bo = (const float*)d_in[9];
    float* out = (float*)d_out;

    const int M = BATCH * S_LEN;   // 8192
    const int K = D_MODEL, N = D_MODEL;
    const size_t tsz = (size_t)M * D_MODEL;   // elements per [B,S,D] tensor

    u16* Qb = (u16*)d_ws;
    u16* Kb = Qb + tsz;
    u16* Vb = Kb + tsz;
    u16* AO = Vb + tsz;            // 4 x 16.78 MB = 67 MB of ws

    dim3 gg(N / 64, M / 128);      // 16 x 64 = 1024 blocks
    gemm_bias<float, u16><<<gg, 256, 0, stream>>>(x, Wq, bq, Qb, M, K, N);
    gemm_bias<float, u16><<<gg, 256, 0, stream>>>(x, Wk, bk, Kb, M, K, N);
    gemm_bias<float, u16><<<gg, 256, 0, stream>>>(x, Wv, bv, Vb, M, K, N);

    const int rows = BATCH * NUM_HEADS * S_LEN;  // 131072 waves
    attn_kernel<<<rows / 4, 256, 0, stream>>>(Qb, Kb, Vb, AO);

    gemm_bias<u16, float><<<gg, 256, 0, stream>>>(AO, Wo, bo, out, M, K, N);
}

// Round 3
// 1110.590 us; speedup vs baseline: 3.7039x; 3.7039x over previous
//
#include <hip/hip_runtime.h>
#include <hip/hip_bf16.h>

#define D_MODEL 1024
#define NUM_HEADS 16
#define D_K 64
#define S_LEN 2048
#define BATCH 4

typedef unsigned short u16;
typedef __attribute__((ext_vector_type(8))) short bf16x8;
typedef __attribute__((ext_vector_type(4))) float f32x4;

__device__ __forceinline__ float bf2f(u16 u) {
    union { unsigned int i; float f; } v; v.i = ((unsigned int)u) << 16; return v.f;
}
__device__ __forceinline__ u16 f2bf(float f) {
    union { unsigned int i; float f; } v; v.f = f;
    unsigned int x = v.i;
    return (u16)((x + 0x7FFFu + ((x >> 16) & 1u)) >> 16); // round-nearest-even
}

// ---------------- GEMM (unchanged from round 1; MFMA-ize next round) ----------------
// C[M,N] = A[M,K] @ W[K,N] + bias[N].
template <typename TA, typename TC>
__global__ __launch_bounds__(256) void gemm_bias(
    const TA* __restrict__ A, const float* __restrict__ W,
    const float* __restrict__ bias, TC* __restrict__ C,
    int M, int K, int N)
{
    __shared__ float As[16][132];
    __shared__ float Bs[16][68];

    const int tid = threadIdx.x;
    const int tx = tid & 15;
    const int ty = tid >> 4;
    const int m0 = blockIdx.y * 128;
    const int n0 = blockIdx.x * 64;

    float acc[8][4] = {};

    for (int k0 = 0; k0 < K; k0 += 16) {
        #pragma unroll
        for (int f = tid; f < 512; f += 256) {
            const int row = f >> 2;
            const int kq  = (f & 3) * 4;
            const TA* ap = A + (size_t)(m0 + row) * K + k0 + kq;
            float v0, v1, v2, v3;
            if constexpr (sizeof(TA) == 4) {
                float4 t = *reinterpret_cast<const float4*>(ap);
                v0 = t.x; v1 = t.y; v2 = t.z; v3 = t.w;
            } else {
                ushort4 t = *reinterpret_cast<const ushort4*>(ap);
                v0 = bf2f(t.x); v1 = bf2f(t.y); v2 = bf2f(t.z); v3 = bf2f(t.w);
            }
            As[kq + 0][row] = v0;
            As[kq + 1][row] = v1;
            As[kq + 2][row] = v2;
            As[kq + 3][row] = v3;
        }
        {
            const int krow = tid >> 4;
            const int nq   = (tid & 15) * 4;
            float4 t = *reinterpret_cast<const float4*>(
                W + (size_t)(k0 + krow) * N + n0 + nq);
            Bs[krow][nq + 0] = t.x;
            Bs[krow][nq + 1] = t.y;
            Bs[krow][nq + 2] = t.z;
            Bs[krow][nq + 3] = t.w;
        }
        __syncthreads();

        #pragma unroll
        for (int kk = 0; kk < 16; ++kk) {
            float ar[8], br[4];
            #pragma unroll
            for (int i = 0; i < 8; ++i) ar[i] = As[kk][ty * 8 + i];
            #pragma unroll
            for (int j = 0; j < 4; ++j) br[j] = Bs[kk][tx * 4 + j];
            #pragma unroll
            for (int i = 0; i < 8; ++i)
                #pragma unroll
                for (int j = 0; j < 4; ++j)
                    acc[i][j] = fmaf(ar[i], br[j], acc[i][j]);
        }
        __syncthreads();
    }

    float bc[4];
    #pragma unroll
    for (int j = 0; j < 4; ++j) bc[j] = bias[n0 + tx * 4 + j];

    #pragma unroll
    for (int i = 0; i < 8; ++i) {
        const int mrow = m0 + ty * 8 + i;
        if constexpr (sizeof(TC) == 4) {
            float4 ov;
            ov.x = acc[i][0] + bc[0];
            ov.y = acc[i][1] + bc[1];
            ov.z = acc[i][2] + bc[2];
            ov.w = acc[i][3] + bc[3];
            *reinterpret_cast<float4*>(&C[(size_t)mrow * N + n0 + tx * 4]) = ov;
        } else {
            ushort4 ov;
            ov.x = f2bf(acc[i][0] + bc[0]);
            ov.y = f2bf(acc[i][1] + bc[1]);
            ov.z = f2bf(acc[i][2] + bc[2]);
            ov.w = f2bf(acc[i][3] + bc[3]);
            *reinterpret_cast<ushort4*>(&C[(size_t)mrow * N + n0 + tx * 4]) = ov;
        }
    }
}

// ---------------- V transpose: Vb[b][j][h*64+d] -> VT[bh][d][j] ----------------
__global__ __launch_bounds__(256) void transpose_v(
    const u16* __restrict__ Vb, u16* __restrict__ VT)
{
    __shared__ u16 T[64 * 65];   // [j][d], +1 u16 pad breaks bank conflicts
    const int i  = blockIdx.x;   // bh*32 + jt
    const int bh = i >> 5, jt = i & 31;
    const int b  = bh >> 4, h = bh & 15;
    const int j0 = jt * 64, hd = h * 64;
    const int tid = threadIdx.x;

    #pragma unroll
    for (int it = 0; it < 2; ++it) {
        int seg = it * 256 + tid;
        int jr = seg >> 3, d0 = (seg & 7) * 8;
        bf16x8 v = *reinterpret_cast<const bf16x8*>(
            Vb + ((size_t)(b * S_LEN + j0 + jr)) * D_MODEL + hd + d0);
        #pragma unroll
        for (int e = 0; e < 8; ++e) T[jr * 65 + d0 + e] = (u16)v[e];
    }
    __syncthreads();
    #pragma unroll
    for (int it = 0; it < 2; ++it) {
        int seg = it * 256 + tid;
        int d = seg >> 3, uj = (seg & 7) * 8;
        bf16x8 o;
        #pragma unroll
        for (int e = 0; e < 8; ++e) o[e] = (short)T[(uj + e) * 65 + d];
        *reinterpret_cast<bf16x8*>(
            VT + ((size_t)bh * 64 + d) * S_LEN + j0 + uj) = o;
    }
}

// ---------------- MFMA flash attention ----------------
// 2048 blocks, 4 waves. Wave w: 16 q-rows. KBLK=64. Causal structural.
// LDS XOR swizzle: logical 16B unit u of row r stored at u^(r&7).
__global__ __launch_bounds__(256) void flash_attn(
    const u16* __restrict__ Qb, const u16* __restrict__ Kb,
    const u16* __restrict__ VT, u16* __restrict__ AO)
{
    __shared__ u16 K_lds[64 * 64];       // [key k][d], swizzled
    __shared__ u16 V_lds[64 * 64];       // [d][key k], swizzled (from VT)
    __shared__ u16 P_lds[4 * 16 * 64];   // per-wave [q][k], swizzled

    // XCD-aware decode: blocks of one bh stay on one XCD (K/V L2-resident).
    const int i   = blockIdx.x;
    const int bh  = (i & 7) * 8 + ((i >> 3) >> 5);
    const int qt  = (i >> 3) & 31;
    const int b   = bh >> 4, h = bh & 15;
    const int hd  = h * 64;

    const int tid  = threadIdx.x;
    const int w    = tid >> 6, lane = tid & 63;
    const int g    = lane >> 4, c16 = lane & 15;

    const int q0 = qt * 64 + w * 16;     // wave's first q row (within b)
    const size_t qrow = ((size_t)b * S_LEN + q0 + c16) * D_MODEL + hd;
    const bf16x8 qf0 = *reinterpret_cast<const bf16x8*>(Qb + qrow + g * 8);
    const bf16x8 qf1 = *reinterpret_cast<const bf16x8*>(Qb + qrow + 32 + g * 8);

    const f32x4 ZERO = {0.f, 0.f, 0.f, 0.f};
    const f32x4 NEGI = {-1e30f, -1e30f, -1e30f, -1e30f};
    f32x4 acc[4];                        // acc[dt][r] : O[q=g*4+r][d=dt*16+c16]
    #pragma unroll
    for (int dt = 0; dt < 4; ++dt) acc[dt] = ZERO;
    float m[4], l[4];
    #pragma unroll
    for (int r = 0; r < 4; ++r) { m[r] = -1e30f; l[r] = 0.f; }

    const size_t kbase  = (size_t)b * S_LEN * D_MODEL + hd;   // Kb rows j
    const size_t vtbase = (size_t)bh * 64 * S_LEN;            // VT rows d
    u16* Pw = &P_lds[w * 1024];

    const int nt = qt + 1;
    for (int jt = 0; jt < nt; ++jt) {
        const int j0 = jt * 64;
        const bool dtile = (jt == qt);

        __syncthreads();
        #pragma unroll
        for (int it = 0; it < 2; ++it) {
            const int seg = it * 256 + tid;
            const int row = seg >> 3, u = seg & 7;
            const bf16x8 kv = *reinterpret_cast<const bf16x8*>(
                Kb + kbase + (size_t)(j0 + row) * D_MODEL + u * 8);
            *reinterpret_cast<bf16x8*>(
                &K_lds[row * 64 + ((u ^ (row & 7)) << 3)]) = kv;
            const bf16x8 vv = *reinterpret_cast<const bf16x8*>(
                VT + vtbase + (size_t)row * S_LEN + j0 + u * 8);
            *reinterpret_cast<bf16x8*>(
                &V_lds[row * 64 + ((u ^ (row & 7)) << 3)]) = vv;
        }
        __syncthreads();

        // ---- QK^T: s[kt][r] = S[q = g*4+r][k = kt*16+c16] * scale ----
        f32x4 s[4];
        #pragma unroll
        for (int kt = 0; kt < 4; ++kt) {
            if (dtile && kt > w) { s[kt] = NEGI; continue; }
            const int row = kt * 16 + c16;
            const bf16x8 kf0 = *reinterpret_cast<const bf16x8*>(
                &K_lds[row * 64 + (((0 + g) ^ (row & 7)) << 3)]);
            const bf16x8 kf1 = *reinterpret_cast<const bf16x8*>(
                &K_lds[row * 64 + (((4 + g) ^ (row & 7)) << 3)]);
            f32x4 t = __builtin_amdgcn_mfma_f32_16x16x32_bf16(qf0, kf0, ZERO, 0, 0, 0);
            t = __builtin_amdgcn_mfma_f32_16x16x32_bf16(qf1, kf1, t, 0, 0, 0);
            t *= 0.125f;   // 1/sqrt(64)
            if (dtile) {
                #pragma unroll
                for (int r = 0; r < 4; ++r)
                    if (kt * 16 + c16 > w * 16 + g * 4 + r) t[r] = -1e30f;
            }
            s[kt] = t;
        }

        // ---- online softmax (per q-row; cols live in the 16 lanes of group g) ----
        float co[4];
        #pragma unroll
        for (int r = 0; r < 4; ++r) {
            float v = fmaxf(fmaxf(s[0][r], s[1][r]), fmaxf(s[2][r], s[3][r]));
            v = fmaxf(v, __shfl_xor(v, 1));
            v = fmaxf(v, __shfl_xor(v, 2));
            v = fmaxf(v, __shfl_xor(v, 4));
            v = fmaxf(v, __shfl_xor(v, 8));
            const float mn = fmaxf(m[r], v);
            co[r] = __expf(m[r] - mn);
            m[r] = mn;
        }
        #pragma unroll
        for (int r = 0; r < 4; ++r) {
            const float p0 = __expf(s[0][r] - m[r]);
            const float p1 = __expf(s[1][r] - m[r]);
            const float p2 = __expf(s[2][r] - m[r]);
            const float p3 = __expf(s[3][r] - m[r]);
            s[0][r] = p0; s[1][r] = p1; s[2][r] = p2; s[3][r] = p3;
            float t = p0 + p1 + p2 + p3;
            t += __shfl_xor(t, 1);
            t += __shfl_xor(t, 2);
            t += __shfl_xor(t, 4);
            t += __shfl_xor(t, 8);
            l[r] = l[r] * co[r] + t;
        }
        #pragma unroll
        for (int dt = 0; dt < 4; ++dt) {
            #pragma unroll
            for (int r = 0; r < 4; ++r) acc[dt][r] *= co[r];
        }

        // ---- P -> LDS (bf16, swizzled), per-wave private ----
        #pragma unroll
        for (int kt = 0; kt < 4; ++kt) {
            #pragma unroll
            for (int r = 0; r < 4; ++r) {
                const int prow = g * 4 + r;
                const int pcol = kt * 16 + c16;
                Pw[prow * 64 + (((pcol >> 3) ^ (prow & 7)) << 3) + (pcol & 7)]
                    = f2bf(s[kt][r]);
            }
        }

        // ---- PV: acc[dt] += P[16x32] * V[32x16(dt)] ----
        #pragma unroll
        for (int c32 = 0; c32 < 2; ++c32) {
            if (dtile && c32 == 1 && w < 2) continue;   // fully masked chunk
            const bf16x8 pf = *reinterpret_cast<const bf16x8*>(
                &Pw[c16 * 64 + (((c32 * 4 + g) ^ (c16 & 7)) << 3)]);
            #pragma unroll
            for (int dt = 0; dt < 4; ++dt) {
                const int vrow = dt * 16 + c16;
                const bf16x8 vf = *reinterpret_cast<const bf16x8*>(
                    &V_lds[vrow * 64 + (((c32 * 4 + g) ^ (vrow & 7)) << 3)]);
                acc[dt] = __builtin_amdgcn_mfma_f32_16x16x32_bf16(pf, vf, acc[dt], 0, 0, 0);
            }
        }
    }

    // ---- epilogue ----
    float inv[4];
    #pragma unroll
    for (int r = 0; r < 4; ++r) inv[r] = 1.f / l[r];
    #pragma unroll
    for (int dt = 0; dt < 4; ++dt) {
        #pragma unroll
        for (int r = 0; r < 4; ++r) {
            const size_t orow =
                ((size_t)b * S_LEN + q0 + g * 4 + r) * D_MODEL + hd + dt * 16 + c16;
            AO[orow] = f2bf(acc[dt][r] * inv[r]);
        }
    }
}

extern "C" void kernel_launch(void* const* d_in, const int* in_sizes, int n_in,
                              void* d_out, int out_size, void* d_ws, size_t ws_size,
                              hipStream_t stream) {
    const float* x  = (const float*)d_in[0];
    // d_in[1] = causal mask: applied structurally — not read.
    const float* Wq = (const float*)d_in[2];
    const float* bq = (const float*)d_in[3];
    const float* Wk = (const float*)d_in[4];
    const float* bk = (const float*)d_in[5];
    const float* Wv = (const float*)d_in[6];
    const float* bv = (const float*)d_in[7];
    const float* Wo = (const float*)d_in[8];
    const float* bo = (const float*)d_in[9];
    float* out = (float*)d_out;

    const int M = BATCH * S_LEN;   // 8192
    const int K = D_MODEL, N = D_MODEL;
    const size_t tsz = (size_t)M * D_MODEL;

    u16* Qb = (u16*)d_ws;
    u16* Kb = Qb + tsz;
    u16* Vb = Kb + tsz;
    u16* AO = Vb + tsz;
    u16* VT = AO + tsz;            // 5 x 16.78 MB = 84 MB of ws

    dim3 gg(N / 64, M / 128);      // 16 x 64
    gemm_bias<float, u16><<<gg, 256, 0, stream>>>(x, Wq, bq, Qb, M, K, N);
    gemm_bias<float, u16><<<gg, 256, 0, stream>>>(x, Wk, bk, Kb, M, K, N);
    gemm_bias<float, u16><<<gg, 256, 0, stream>>>(x, Wv, bv, Vb, M, K, N);

    transpose_v<<<2048, 256, 0, stream>>>(Vb, VT);
    flash_attn<<<2048, 256, 0, stream>>>(Qb, Kb, VT, AO);

    gemm_bias<u16, float><<<gg, 256, 0, stream>>>(AO, Wo, bo, out, M, K, N);
}

// Round 4
// 290.720 us; speedup vs baseline: 14.1495x; 3.8201x over previous
//
#include <hip/hip_runtime.h>
#include <hip/hip_bf16.h>

#define D_MODEL 1024
#define NUM_HEADS 16
#define D_K 64
#define S_LEN 2048
#define BATCH 4

typedef unsigned short u16;
typedef __attribute__((ext_vector_type(8))) short bf16x8;
typedef __attribute__((ext_vector_type(4))) float f32x4;

#define MFMA16 __builtin_amdgcn_mfma_f32_16x16x32_bf16

__device__ __forceinline__ float bf2f(u16 u) {
    union { unsigned int i; float f; } v; v.i = ((unsigned int)u) << 16; return v.f;
}
__device__ __forceinline__ u16 f2bf(float f) {
    union { unsigned int i; float f; } v; v.f = f;
    unsigned int x = v.i;
    return (u16)((x + 0x7FFFu + ((x >> 16) & 1u)) >> 16); // round-nearest-even
}

__device__ __forceinline__ void gload16(const u16* g, u16* l) {
    __builtin_amdgcn_global_load_lds(
        (const __attribute__((address_space(1))) unsigned int*)g,
        (__attribute__((address_space(3))) unsigned int*)l, 16, 0, 0);
}

// ---------------- prep: x fp32 -> bf16 ----------------
__global__ __launch_bounds__(256) void convert_x(
    const float* __restrict__ x, u16* __restrict__ xb)
{
    const size_t i = ((size_t)blockIdx.x * 256 + threadIdx.x) * 8;
    float4 a = *reinterpret_cast<const float4*>(x + i);
    float4 b = *reinterpret_cast<const float4*>(x + i + 4);
    bf16x8 o;
    o[0] = (short)f2bf(a.x); o[1] = (short)f2bf(a.y);
    o[2] = (short)f2bf(a.z); o[3] = (short)f2bf(a.w);
    o[4] = (short)f2bf(b.x); o[5] = (short)f2bf(b.y);
    o[6] = (short)f2bf(b.z); o[7] = (short)f2bf(b.w);
    *reinterpret_cast<bf16x8*>(xb + i) = o;
}

// ---------------- prep: W[k][n] fp32 -> WT[n][k] bf16 (4 matrices) ----------------
__global__ __launch_bounds__(256) void transpose_w(
    const float* __restrict__ W0, const float* __restrict__ W1,
    const float* __restrict__ W2, const float* __restrict__ W3,
    u16* __restrict__ T0, u16* __restrict__ T1,
    u16* __restrict__ T2, u16* __restrict__ T3)
{
    const float* W; u16* T;
    switch (blockIdx.z & 3) {
        case 0:  W = W0; T = T0; break;
        case 1:  W = W1; T = T1; break;
        case 2:  W = W2; T = T2; break;
        default: W = W3; T = T3; break;
    }
    __shared__ u16 S[64][72];
    const int tid = threadIdx.x;
    const int k0 = blockIdx.y * 64, n0 = blockIdx.x * 64;

    const int k = tid >> 2, nb = (tid & 3) * 16;
    #pragma unroll
    for (int c = 0; c < 4; ++c) {
        float4 v = *reinterpret_cast<const float4*>(
            W + (size_t)(k0 + k) * D_MODEL + n0 + nb + c * 4);
        S[nb + c * 4 + 0][k] = f2bf(v.x);
        S[nb + c * 4 + 1][k] = f2bf(v.y);
        S[nb + c * 4 + 2][k] = f2bf(v.z);
        S[nb + c * 4 + 3][k] = f2bf(v.w);
    }
    __syncthreads();
    const int n = tid >> 2, kb = (tid & 3) * 16;
    #pragma unroll
    for (int c = 0; c < 2; ++c) {
        bf16x8 o;
        #pragma unroll
        for (int e = 0; e < 8; ++e) o[e] = (short)S[n][kb + c * 8 + e];
        *reinterpret_cast<bf16x8*>(T + (size_t)(n0 + n) * D_MODEL + k0 + kb + c * 8) = o;
    }
}

// ---------------- MFMA GEMM: C[8192,1024] = A[8192,1024] @ BT[1024,1024]^T + bias ----------------
// 128x128 tile, BK=64, 4 waves (2x2), 64x64 per wave, 16x16x32 MFMA.
// LDS rows are 64 bf16 = 128 B; unit u (16 B) of row r stored at u^(r&7)
// (both-sides swizzle: pre-swizzled global source + swizzled read; dest linear).
template <typename TC>
__device__ __forceinline__ void gemm_body(
    const u16* __restrict__ A, const u16* __restrict__ BT,
    const float* __restrict__ bias, TC* __restrict__ C,
    u16* Al, u16* Bl)
{
    const int tid = threadIdx.x;
    const int w = tid >> 6, lane = tid & 63;
    const int g = lane >> 4, c16 = lane & 15;
    const int wr = w >> 1, wc = w & 1;
    const int m0 = blockIdx.y * 128, n0 = blockIdx.x * 128;

    // staging coords (constant across K-steps): phys unit p = i*256+tid
    int rS[4], uS[4];
    #pragma unroll
    for (int i = 0; i < 4; ++i) {
        const int p = i * 256 + tid;
        rS[i] = p >> 3;
        uS[i] = ((p & 7) ^ (rS[i] & 7)) * 8;   // element offset of logical unit
    }

    f32x4 acc[4][4];
    #pragma unroll
    for (int mi = 0; mi < 4; ++mi)
        #pragma unroll
        for (int ni = 0; ni < 4; ++ni) acc[mi][ni] = (f32x4){0.f, 0.f, 0.f, 0.f};

    for (int k0 = 0; k0 < D_MODEL; k0 += 64) {
        #pragma unroll
        for (int i = 0; i < 4; ++i) {
            u16* ldst = Al + (size_t)(i * 256 + w * 64) * 8;
            gload16(A + (size_t)(m0 + rS[i]) * D_MODEL + k0 + uS[i], ldst);
            u16* ldstB = Bl + (size_t)(i * 256 + w * 64) * 8;
            gload16(BT + (size_t)(n0 + rS[i]) * D_MODEL + k0 + uS[i], ldstB);
        }
        __syncthreads();   // compiler drains vmcnt before s_barrier

        #pragma unroll
        for (int s = 0; s < 2; ++s) {
            bf16x8 af[4], bfr[4];
            #pragma unroll
            for (int mi = 0; mi < 4; ++mi) {
                const int r = wr * 64 + mi * 16 + c16;
                af[mi] = *reinterpret_cast<const bf16x8*>(
                    &Al[((r << 3) + ((s * 4 + g) ^ (r & 7))) * 8]);
            }
            #pragma unroll
            for (int ni = 0; ni < 4; ++ni) {
                const int r = wc * 64 + ni * 16 + c16;
                bfr[ni] = *reinterpret_cast<const bf16x8*>(
                    &Bl[((r << 3) + ((s * 4 + g) ^ (r & 7))) * 8]);
            }
            #pragma unroll
            for (int mi = 0; mi < 4; ++mi)
                #pragma unroll
                for (int ni = 0; ni < 4; ++ni)
                    acc[mi][ni] = MFMA16(af[mi], bfr[ni], acc[mi][ni], 0, 0, 0);
        }
        __syncthreads();   // before next stage overwrites LDS
    }

    float bc[4];
    #pragma unroll
    for (int ni = 0; ni < 4; ++ni) bc[ni] = bias[n0 + wc * 64 + ni * 16 + c16];

    #pragma unroll
    for (int mi = 0; mi < 4; ++mi) {
        #pragma unroll
        for (int ni = 0; ni < 4; ++ni) {
            const int col = n0 + wc * 64 + ni * 16 + c16;
            #pragma unroll
            for (int r = 0; r < 4; ++r) {
                const int row = m0 + wr * 64 + mi * 16 + g * 4 + r;
                const float v = acc[mi][ni][r] + bc[ni];
                if constexpr (sizeof(TC) == 4) {
                    C[(size_t)row * D_MODEL + col] = v;
                } else {
                    C[(size_t)row * D_MODEL + col] = f2bf(v);
                }
            }
        }
    }
}

__global__ __launch_bounds__(256) void gemm_qkv(
    const u16* __restrict__ A,
    const u16* __restrict__ BTq, const u16* __restrict__ BTk, const u16* __restrict__ BTv,
    const float* __restrict__ bq, const float* __restrict__ bk, const float* __restrict__ bv,
    u16* __restrict__ Cq, u16* __restrict__ Ck, u16* __restrict__ Cv)
{
    __shared__ u16 Al[128 * 64];
    __shared__ u16 Bl[128 * 64];
    const u16* BT; const float* bias; u16* C;
    switch (blockIdx.z) {
        case 0:  BT = BTq; bias = bq; C = Cq; break;
        case 1:  BT = BTk; bias = bk; C = Ck; break;
        default: BT = BTv; bias = bv; C = Cv; break;
    }
    gemm_body<u16>(A, BT, bias, C, Al, Bl);
}

__global__ __launch_bounds__(256) void gemm_out(
    const u16* __restrict__ A, const u16* __restrict__ BT,
    const float* __restrict__ bias, float* __restrict__ C)
{
    __shared__ u16 Al[128 * 64];
    __shared__ u16 Bl[128 * 64];
    gemm_body<float>(A, BT, bias, C, Al, Bl);
}

// ---------------- V transpose: Vb[b][j][h*64+d] -> VT[bh][d][j] ----------------
__global__ __launch_bounds__(256) void transpose_v(
    const u16* __restrict__ Vb, u16* __restrict__ VT)
{
    __shared__ u16 T[64 * 65];
    const int i  = blockIdx.x;   // bh*32 + jt
    const int bh = i >> 5, jt = i & 31;
    const int b  = bh >> 4, h = bh & 15;
    const int j0 = jt * 64, hd = h * 64;
    const int tid = threadIdx.x;

    #pragma unroll
    for (int it = 0; it < 2; ++it) {
        int seg = it * 256 + tid;
        int jr = seg >> 3, d0 = (seg & 7) * 8;
        bf16x8 v = *reinterpret_cast<const bf16x8*>(
            Vb + ((size_t)(b * S_LEN + j0 + jr)) * D_MODEL + hd + d0);
        #pragma unroll
        for (int e = 0; e < 8; ++e) T[jr * 65 + d0 + e] = (u16)v[e];
    }
    __syncthreads();
    #pragma unroll
    for (int it = 0; it < 2; ++it) {
        int seg = it * 256 + tid;
        int d = seg >> 3, uj = (seg & 7) * 8;
        bf16x8 o;
        #pragma unroll
        for (int e = 0; e < 8; ++e) o[e] = (short)T[(uj + e) * 65 + d];
        *reinterpret_cast<bf16x8*>(
            VT + ((size_t)bh * 64 + d) * S_LEN + j0 + uj) = o;
    }
}

// ---------------- MFMA flash attention (unchanged from round 2) ----------------
__global__ __launch_bounds__(256) void flash_attn(
    const u16* __restrict__ Qb, const u16* __restrict__ Kb,
    const u16* __restrict__ VT, u16* __restrict__ AO)
{
    __shared__ u16 K_lds[64 * 64];
    __shared__ u16 V_lds[64 * 64];
    __shared__ u16 P_lds[4 * 16 * 64];

    const int i   = blockIdx.x;
    const int bh  = (i & 7) * 8 + ((i >> 3) >> 5);
    const int qt  = (i >> 3) & 31;
    const int b   = bh >> 4, h = bh & 15;
    const int hd  = h * 64;

    const int tid  = threadIdx.x;
    const int w    = tid >> 6, lane = tid & 63;
    const int g    = lane >> 4, c16 = lane & 15;

    const int q0 = qt * 64 + w * 16;
    const size_t qrow = ((size_t)b * S_LEN + q0 + c16) * D_MODEL + hd;
    const bf16x8 qf0 = *reinterpret_cast<const bf16x8*>(Qb + qrow + g * 8);
    const bf16x8 qf1 = *reinterpret_cast<const bf16x8*>(Qb + qrow + 32 + g * 8);

    const f32x4 ZERO = {0.f, 0.f, 0.f, 0.f};
    const f32x4 NEGI = {-1e30f, -1e30f, -1e30f, -1e30f};
    f32x4 acc[4];
    #pragma unroll
    for (int dt = 0; dt < 4; ++dt) acc[dt] = ZERO;
    float m[4], l[4];
    #pragma unroll
    for (int r = 0; r < 4; ++r) { m[r] = -1e30f; l[r] = 0.f; }

    const size_t kbase  = (size_t)b * S_LEN * D_MODEL + hd;
    const size_t vtbase = (size_t)bh * 64 * S_LEN;
    u16* Pw = &P_lds[w * 1024];

    const int nt = qt + 1;
    for (int jt = 0; jt < nt; ++jt) {
        const int j0 = jt * 64;
        const bool dtile = (jt == qt);

        __syncthreads();
        #pragma unroll
        for (int it = 0; it < 2; ++it) {
            const int seg = it * 256 + tid;
            const int row = seg >> 3, u = seg & 7;
            const bf16x8 kv = *reinterpret_cast<const bf16x8*>(
                Kb + kbase + (size_t)(j0 + row) * D_MODEL + u * 8);
            *reinterpret_cast<bf16x8*>(
                &K_lds[row * 64 + ((u ^ (row & 7)) << 3)]) = kv;
            const bf16x8 vv = *reinterpret_cast<const bf16x8*>(
                VT + vtbase + (size_t)row * S_LEN + j0 + u * 8);
            *reinterpret_cast<bf16x8*>(
                &V_lds[row * 64 + ((u ^ (row & 7)) << 3)]) = vv;
        }
        __syncthreads();

        f32x4 s[4];
        #pragma unroll
        for (int kt = 0; kt < 4; ++kt) {
            if (dtile && kt > w) { s[kt] = NEGI; continue; }
            const int row = kt * 16 + c16;
            const bf16x8 kf0 = *reinterpret_cast<const bf16x8*>(
                &K_lds[row * 64 + (((0 + g) ^ (row & 7)) << 3)]);
            const bf16x8 kf1 = *reinterpret_cast<const bf16x8*>(
                &K_lds[row * 64 + (((4 + g) ^ (row & 7)) << 3)]);
            f32x4 t = MFMA16(qf0, kf0, ZERO, 0, 0, 0);
            t = MFMA16(qf1, kf1, t, 0, 0, 0);
            t *= 0.125f;
            if (dtile) {
                #pragma unroll
                for (int r = 0; r < 4; ++r)
                    if (kt * 16 + c16 > w * 16 + g * 4 + r) t[r] = -1e30f;
            }
            s[kt] = t;
        }

        float co[4];
        #pragma unroll
        for (int r = 0; r < 4; ++r) {
            float v = fmaxf(fmaxf(s[0][r], s[1][r]), fmaxf(s[2][r], s[3][r]));
            v = fmaxf(v, __shfl_xor(v, 1));
            v = fmaxf(v, __shfl_xor(v, 2));
            v = fmaxf(v, __shfl_xor(v, 4));
            v = fmaxf(v, __shfl_xor(v, 8));
            const float mn = fmaxf(m[r], v);
            co[r] = __expf(m[r] - mn);
            m[r] = mn;
        }
        #pragma unroll
        for (int r = 0; r < 4; ++r) {
            const float p0 = __expf(s[0][r] - m[r]);
            const float p1 = __expf(s[1][r] - m[r]);
            const float p2 = __expf(s[2][r] - m[r]);
            const float p3 = __expf(s[3][r] - m[r]);
            s[0][r] = p0; s[1][r] = p1; s[2][r] = p2; s[3][r] = p3;
            float t = p0 + p1 + p2 + p3;
            t += __shfl_xor(t, 1);
            t += __shfl_xor(t, 2);
            t += __shfl_xor(t, 4);
            t += __shfl_xor(t, 8);
            l[r] = l[r] * co[r] + t;
        }
        #pragma unroll
        for (int dt = 0; dt < 4; ++dt) {
            #pragma unroll
            for (int r = 0; r < 4; ++r) acc[dt][r] *= co[r];
        }

        #pragma unroll
        for (int kt = 0; kt < 4; ++kt) {
            #pragma unroll
            for (int r = 0; r < 4; ++r) {
                const int prow = g * 4 + r;
                const int pcol = kt * 16 + c16;
                Pw[prow * 64 + (((pcol >> 3) ^ (prow & 7)) << 3) + (pcol & 7)]
                    = f2bf(s[kt][r]);
            }
        }

        #pragma unroll
        for (int c32 = 0; c32 < 2; ++c32) {
            if (dtile && c32 == 1 && w < 2) continue;
            const bf16x8 pf = *reinterpret_cast<const bf16x8*>(
                &Pw[c16 * 64 + (((c32 * 4 + g) ^ (c16 & 7)) << 3)]);
            #pragma unroll
            for (int dt = 0; dt < 4; ++dt) {
                const int vrow = dt * 16 + c16;
                const bf16x8 vf = *reinterpret_cast<const bf16x8*>(
                    &V_lds[vrow * 64 + (((c32 * 4 + g) ^ (vrow & 7)) << 3)]);
                acc[dt] = MFMA16(pf, vf, acc[dt], 0, 0, 0);
            }
        }
    }

    float inv[4];
    #pragma unroll
    for (int r = 0; r < 4; ++r) inv[r] = 1.f / l[r];
    #pragma unroll
    for (int dt = 0; dt < 4; ++dt) {
        #pragma unroll
        for (int r = 0; r < 4; ++r) {
            const size_t orow =
                ((size_t)b * S_LEN + q0 + g * 4 + r) * D_MODEL + hd + dt * 16 + c16;
            AO[orow] = f2bf(acc[dt][r] * inv[r]);
        }
    }
}

extern "C" void kernel_launch(void* const* d_in, const int* in_sizes, int n_in,
                              void* d_out, int out_size, void* d_ws, size_t ws_size,
                              hipStream_t stream) {
    const float* x  = (const float*)d_in[0];
    // d_in[1] = causal mask: applied structurally — not read.
    const float* Wq = (const float*)d_in[2];
    const float* bq = (const float*)d_in[3];
    const float* Wk = (const float*)d_in[4];
    const float* bk = (const float*)d_in[5];
    const float* Wv = (const float*)d_in[6];
    const float* bv = (const float*)d_in[7];
    const float* Wo = (const float*)d_in[8];
    const float* bo = (const float*)d_in[9];
    float* out = (float*)d_out;

    const int M = BATCH * S_LEN;              // 8192
    const size_t tsz = (size_t)M * D_MODEL;   // 8.4M elems
    const size_t wsz = (size_t)D_MODEL * D_MODEL;

    u16* xb  = (u16*)d_ws;
    u16* Qb  = xb + tsz;
    u16* Kb  = Qb + tsz;
    u16* Vb  = Kb + tsz;
    u16* VT  = Vb + tsz;
    u16* WTq = VT + tsz;
    u16* WTk = WTq + wsz;
    u16* WTv = WTk + wsz;
    u16* WTo = WTv + wsz;      // total ~92 MB
    u16* AO  = Vb;             // Vb dead after transpose_v

    convert_x<<<(int)(tsz / (256 * 8)), 256, 0, stream>>>(x, xb);
    transpose_w<<<dim3(16, 16, 4), 256, 0, stream>>>(
        Wq, Wk, Wv, Wo, WTq, WTk, WTv, WTo);

    gemm_qkv<<<dim3(8, 64, 3), 256, 0, stream>>>(
        xb, WTq, WTk, WTv, bq, bk, bv, Qb, Kb, Vb);

    transpose_v<<<2048, 256, 0, stream>>>(Vb, VT);
    flash_attn<<<2048, 256, 0, stream>>>(Qb, Kb, VT, AO);

    gemm_out<<<dim3(8, 64), 256, 0, stream>>>(AO, WTo, bo, out);
}

// Round 5
// 206.335 us; speedup vs baseline: 19.9362x; 1.4090x over previous
//
#include <hip/hip_runtime.h>
#include <hip/hip_bf16.h>

#define D_MODEL 1024
#define NUM_HEADS 16
#define D_K 64
#define S_LEN 2048
#define BATCH 4

typedef unsigned short u16;
typedef __attribute__((ext_vector_type(8))) short bf16x8;
typedef __attribute__((ext_vector_type(4))) float f32x4;

#define MFMA16 __builtin_amdgcn_mfma_f32_16x16x32_bf16

// fold attn scale + ln2 conversion into the Q projection: 0.125 * log2(e)
#define Q_SCALE 0.18033688011112042f

__device__ __forceinline__ float bf2f(u16 u) {
    union { unsigned int i; float f; } v; v.i = ((unsigned int)u) << 16; return v.f;
}
__device__ __forceinline__ u16 f2bf(float f) {
    union { unsigned int i; float f; } v; v.f = f;
    unsigned int x = v.i;
    return (u16)((x + 0x7FFFu + ((x >> 16) & 1u)) >> 16); // round-nearest-even
}

__device__ __forceinline__ void gload16(const u16* g, u16* l) {
    __builtin_amdgcn_global_load_lds(
        (const __attribute__((address_space(1))) unsigned int*)g,
        (__attribute__((address_space(3))) unsigned int*)l, 16, 0, 0);
}

// ---------------- prep: x fp32 -> bf16 ----------------
__global__ __launch_bounds__(256) void convert_x(
    const float* __restrict__ x, u16* __restrict__ xb)
{
    const size_t i = ((size_t)blockIdx.x * 256 + threadIdx.x) * 8;
    float4 a = *reinterpret_cast<const float4*>(x + i);
    float4 b = *reinterpret_cast<const float4*>(x + i + 4);
    bf16x8 o;
    o[0] = (short)f2bf(a.x); o[1] = (short)f2bf(a.y);
    o[2] = (short)f2bf(a.z); o[3] = (short)f2bf(a.w);
    o[4] = (short)f2bf(b.x); o[5] = (short)f2bf(b.y);
    o[6] = (short)f2bf(b.z); o[7] = (short)f2bf(b.w);
    *reinterpret_cast<bf16x8*>(xb + i) = o;
}

// ---------------- prep: W[k][n] fp32 -> WT[n][k] bf16 (4 matrices) ----------------
__global__ __launch_bounds__(256) void transpose_w(
    const float* __restrict__ W0, const float* __restrict__ W1,
    const float* __restrict__ W2, const float* __restrict__ W3,
    u16* __restrict__ T0, u16* __restrict__ T1,
    u16* __restrict__ T2, u16* __restrict__ T3)
{
    const float* W; u16* T;
    switch (blockIdx.z & 3) {
        case 0:  W = W0; T = T0; break;
        case 1:  W = W1; T = T1; break;
        case 2:  W = W2; T = T2; break;
        default: W = W3; T = T3; break;
    }
    __shared__ u16 S[64][72];
    const int tid = threadIdx.x;
    const int k0 = blockIdx.y * 64, n0 = blockIdx.x * 64;

    const int k = tid >> 2, nb = (tid & 3) * 16;
    #pragma unroll
    for (int c = 0; c < 4; ++c) {
        float4 v = *reinterpret_cast<const float4*>(
            W + (size_t)(k0 + k) * D_MODEL + n0 + nb + c * 4);
        S[nb + c * 4 + 0][k] = f2bf(v.x);
        S[nb + c * 4 + 1][k] = f2bf(v.y);
        S[nb + c * 4 + 2][k] = f2bf(v.z);
        S[nb + c * 4 + 3][k] = f2bf(v.w);
    }
    __syncthreads();
    const int n = tid >> 2, kb = (tid & 3) * 16;
    #pragma unroll
    for (int c = 0; c < 2; ++c) {
        bf16x8 o;
        #pragma unroll
        for (int e = 0; e < 8; ++e) o[e] = (short)S[n][kb + c * 8 + e];
        *reinterpret_cast<bf16x8*>(T + (size_t)(n0 + n) * D_MODEL + k0 + kb + c * 8) = o;
    }
}

// ---------------- MFMA GEMM: C = A[8192,1024] @ BT[1024,1024]^T + bias, then *oscale ----------------
template <typename TC>
__device__ __forceinline__ void gemm_body(
    const u16* __restrict__ A, const u16* __restrict__ BT,
    const float* __restrict__ bias, TC* __restrict__ C,
    u16* Al, u16* Bl, float oscale)
{
    const int tid = threadIdx.x;
    const int w = tid >> 6, lane = tid & 63;
    const int g = lane >> 4, c16 = lane & 15;
    const int wr = w >> 1, wc = w & 1;
    const int m0 = blockIdx.y * 128, n0 = blockIdx.x * 128;

    int rS[4], uS[4];
    #pragma unroll
    for (int i = 0; i < 4; ++i) {
        const int p = i * 256 + tid;
        rS[i] = p >> 3;
        uS[i] = ((p & 7) ^ (rS[i] & 7)) * 8;
    }

    f32x4 acc[4][4];
    #pragma unroll
    for (int mi = 0; mi < 4; ++mi)
        #pragma unroll
        for (int ni = 0; ni < 4; ++ni) acc[mi][ni] = (f32x4){0.f, 0.f, 0.f, 0.f};

    for (int k0 = 0; k0 < D_MODEL; k0 += 64) {
        #pragma unroll
        for (int i = 0; i < 4; ++i) {
            gload16(A + (size_t)(m0 + rS[i]) * D_MODEL + k0 + uS[i],
                    Al + (size_t)(i * 256 + w * 64) * 8);
            gload16(BT + (size_t)(n0 + rS[i]) * D_MODEL + k0 + uS[i],
                    Bl + (size_t)(i * 256 + w * 64) * 8);
        }
        __syncthreads();

        #pragma unroll
        for (int s = 0; s < 2; ++s) {
            bf16x8 af[4], bfr[4];
            #pragma unroll
            for (int mi = 0; mi < 4; ++mi) {
                const int r = wr * 64 + mi * 16 + c16;
                af[mi] = *reinterpret_cast<const bf16x8*>(
                    &Al[((r << 3) + ((s * 4 + g) ^ (r & 7))) * 8]);
            }
            #pragma unroll
            for (int ni = 0; ni < 4; ++ni) {
                const int r = wc * 64 + ni * 16 + c16;
                bfr[ni] = *reinterpret_cast<const bf16x8*>(
                    &Bl[((r << 3) + ((s * 4 + g) ^ (r & 7))) * 8]);
            }
            #pragma unroll
            for (int mi = 0; mi < 4; ++mi)
                #pragma unroll
                for (int ni = 0; ni < 4; ++ni)
                    acc[mi][ni] = MFMA16(af[mi], bfr[ni], acc[mi][ni], 0, 0, 0);
        }
        __syncthreads();
    }

    float bc[4];
    #pragma unroll
    for (int ni = 0; ni < 4; ++ni) bc[ni] = bias[n0 + wc * 64 + ni * 16 + c16];

    #pragma unroll
    for (int mi = 0; mi < 4; ++mi) {
        #pragma unroll
        for (int ni = 0; ni < 4; ++ni) {
            const int col = n0 + wc * 64 + ni * 16 + c16;
            #pragma unroll
            for (int r = 0; r < 4; ++r) {
                const int row = m0 + wr * 64 + mi * 16 + g * 4 + r;
                const float v = (acc[mi][ni][r] + bc[ni]) * oscale;
                if constexpr (sizeof(TC) == 4) {
                    C[(size_t)row * D_MODEL + col] = v;
                } else {
                    C[(size_t)row * D_MODEL + col] = f2bf(v);
                }
            }
        }
    }
}

__global__ __launch_bounds__(256) void gemm_qkv(
    const u16* __restrict__ A,
    const u16* __restrict__ BTq, const u16* __restrict__ BTk, const u16* __restrict__ BTv,
    const float* __restrict__ bq, const float* __restrict__ bk, const float* __restrict__ bv,
    u16* __restrict__ Cq, u16* __restrict__ Ck, u16* __restrict__ Cv)
{
    __shared__ u16 Al[128 * 64];
    __shared__ u16 Bl[128 * 64];
    const u16* BT; const float* bias; u16* C; float sc;
    switch (blockIdx.z) {
        case 0:  BT = BTq; bias = bq; C = Cq; sc = Q_SCALE; break;
        case 1:  BT = BTk; bias = bk; C = Ck; sc = 1.f; break;
        default: BT = BTv; bias = bv; C = Cv; sc = 1.f; break;
    }
    gemm_body<u16>(A, BT, bias, C, Al, Bl, sc);
}

__global__ __launch_bounds__(256) void gemm_out(
    const u16* __restrict__ A, const u16* __restrict__ BT,
    const float* __restrict__ bias, float* __restrict__ C)
{
    __shared__ u16 Al[128 * 64];
    __shared__ u16 Bl[128 * 64];
    gemm_body<float>(A, BT, bias, C, Al, Bl, 1.f);
}

// ---------------- V transpose: Vb[b][j][h*64+d] -> VT[bh][d][j] ----------------
__global__ __launch_bounds__(256) void transpose_v(
    const u16* __restrict__ Vb, u16* __restrict__ VT)
{
    __shared__ u16 T[64 * 65];
    const int i  = blockIdx.x;
    const int bh = i >> 5, jt = i & 31;
    const int b  = bh >> 4, h = bh & 15;
    const int j0 = jt * 64, hd = h * 64;
    const int tid = threadIdx.x;

    #pragma unroll
    for (int it = 0; it < 2; ++it) {
        int seg = it * 256 + tid;
        int jr = seg >> 3, d0 = (seg & 7) * 8;
        bf16x8 v = *reinterpret_cast<const bf16x8*>(
            Vb + ((size_t)(b * S_LEN + j0 + jr)) * D_MODEL + hd + d0);
        #pragma unroll
        for (int e = 0; e < 8; ++e) T[jr * 65 + d0 + e] = (u16)v[e];
    }
    __syncthreads();
    #pragma unroll
    for (int it = 0; it < 2; ++it) {
        int seg = it * 256 + tid;
        int d = seg >> 3, uj = (seg & 7) * 8;
        bf16x8 o;
        #pragma unroll
        for (int e = 0; e < 8; ++e) o[e] = (short)T[(uj + e) * 65 + d];
        *reinterpret_cast<bf16x8*>(
            VT + ((size_t)bh * 64 + d) * S_LEN + j0 + uj) = o;
    }
}

// ---------------- MFMA flash attention, swapped-QK^T, paired q-tiles ----------------
// 1024 blocks: (xcd, bh_local, pair). Block does q-tiles {pair, 31-pair}: uniform 33 K-tiles.
// Wave w owns 16 q-rows. Scores arrive in log2 domain (Q pre-scaled by 0.125*log2e).
__global__ __launch_bounds__(256) void flash_attn(
    const u16* __restrict__ Qb, const u16* __restrict__ Kb,
    const u16* __restrict__ VT, u16* __restrict__ AO)
{
    __shared__ u16 K_lds[64 * 64];       // [key j][d], XOR-swizzled 16B units
    __shared__ u16 V_lds[64 * 64];       // [d][key j], XOR-swizzled
    __shared__ u16 P_lds[4 * 16 * 64];   // per-wave [q][j], XOR-swizzled

    const int i    = blockIdx.x;
    const int bh   = (i & 7) * 8 + ((i >> 3) >> 4);   // same-bh blocks share an XCD
    const int pair = (i >> 3) & 15;
    const int b    = bh >> 4, h = bh & 15, hd = h * 64;

    const int tid = threadIdx.x;
    const int w = tid >> 6, lane = tid & 63;
    const int g = lane >> 4, c16 = lane & 15;

    const size_t kbase  = (size_t)b * S_LEN * D_MODEL + hd;
    const size_t vtbase = (size_t)bh * 64 * S_LEN;
    u16* Pw = &P_lds[w * 1024];

    const f32x4 ZERO = {0.f, 0.f, 0.f, 0.f};
    const f32x4 NEGI = {-1e30f, -1e30f, -1e30f, -1e30f};

    // staging coords: phys 16B unit p -> row r=p>>3, logical unit (p&7)^(r&7)
    int rS[2], uS[2];
    #pragma unroll
    for (int it = 0; it < 2; ++it) {
        const int p = it * 256 + tid;
        rS[it] = p >> 3;
        uS[it] = ((p & 7) ^ (rS[it] & 7)) * 8;
    }

    #pragma unroll
    for (int half = 0; half < 2; ++half) {
        const int qt = half ? (31 - pair) : pair;
        const int q0 = qt * 64 + w * 16;

        const size_t qrow = ((size_t)b * S_LEN + q0 + c16) * D_MODEL + hd;
        const bf16x8 qf0 = *reinterpret_cast<const bf16x8*>(Qb + qrow + g * 8);
        const bf16x8 qf1 = *reinterpret_cast<const bf16x8*>(Qb + qrow + 32 + g * 8);

        f32x4 acc[4];
        #pragma unroll
        for (int dt = 0; dt < 4; ++dt) acc[dt] = ZERO;
        float m = -1e30f, lp = 0.f;     // per-lane: row q=c16; lp = partial l over this lane's j-cols

        const int nt = qt + 1;
        for (int jt = 0; jt < nt; ++jt) {
            const int j0 = jt * 64;
            const bool dtile = (jt == qt);

            __syncthreads();
            #pragma unroll
            for (int it = 0; it < 2; ++it) {
                const int p = it * 256 + tid;
                gload16(Kb + kbase + (size_t)(j0 + rS[it]) * D_MODEL + uS[it],
                        K_lds + (size_t)p * 8);
                gload16(VT + vtbase + (size_t)rS[it] * S_LEN + j0 + uS[it],
                        V_lds + (size_t)p * 8);
            }
            __syncthreads();

            // ---- QK^T swapped: st[kt][r] = S[q=c16][j = kt*16 + g*4 + r] (log2 domain) ----
            f32x4 st[4];
            #pragma unroll
            for (int kt = 0; kt < 4; ++kt) {
                if (dtile && kt > w) { st[kt] = NEGI; continue; }
                const int row = kt * 16 + c16;
                const bf16x8 kf0 = *reinterpret_cast<const bf16x8*>(
                    &K_lds[row * 64 + ((g ^ (row & 7)) << 3)]);
                const bf16x8 kf1 = *reinterpret_cast<const bf16x8*>(
                    &K_lds[row * 64 + (((4 + g) ^ (row & 7)) << 3)]);
                f32x4 t = MFMA16(kf0, qf0, ZERO, 0, 0, 0);
                t = MFMA16(kf1, qf1, t, 0, 0, 0);
                if (dtile && kt == w) {
                    #pragma unroll
                    for (int r = 0; r < 4; ++r)
                        if (g * 4 + r > c16) t[r] = -1e30f;
                }
                st[kt] = t;
            }

            // ---- in-lane row max + 2 shfl ----
            float mx = st[0][0];
            #pragma unroll
            for (int kt = 0; kt < 4; ++kt)
                #pragma unroll
                for (int r = 0; r < 4; ++r) mx = fmaxf(mx, st[kt][r]);
            mx = fmaxf(mx, __shfl_xor(mx, 16));
            mx = fmaxf(mx, __shfl_xor(mx, 32));

            // ---- defer-max rescale (rare) ----
            if (__any(mx > m + 11.5f)) {
                const float mn = fmaxf(m, mx);
                const float co = __builtin_amdgcn_exp2f(m - mn);
                lp *= co;
                m = mn;
                float cor[4];
                #pragma unroll
                for (int r = 0; r < 4; ++r) cor[r] = __shfl(co, g * 4 + r);
                #pragma unroll
                for (int dt = 0; dt < 4; ++dt)
                    #pragma unroll
                    for (int r = 0; r < 4; ++r) acc[dt][r] *= cor[r];
            }

            // ---- p = exp2(s - m); accumulate l in-lane; P -> LDS as b64 writes ----
            float tsum = 0.f;
            #pragma unroll
            for (int kt = 0; kt < 4; ++kt) {
                const float p0 = __builtin_amdgcn_exp2f(st[kt][0] - m);
                const float p1 = __builtin_amdgcn_exp2f(st[kt][1] - m);
                const float p2 = __builtin_amdgcn_exp2f(st[kt][2] - m);
                const float p3 = __builtin_amdgcn_exp2f(st[kt][3] - m);
                tsum += (p0 + p1) + (p2 + p3);
                ushort4 pw;
                pw.x = f2bf(p0); pw.y = f2bf(p1); pw.z = f2bf(p2); pw.w = f2bf(p3);
                const int u = kt * 2 + (g >> 1);
                *reinterpret_cast<ushort4*>(
                    &Pw[c16 * 64 + ((u ^ (c16 & 7)) << 3) + (g & 1) * 4]) = pw;
            }
            lp += tsum;

            // ---- PV: acc[dt] += P[16x32] * V[32x16] ----
            #pragma unroll
            for (int c32 = 0; c32 < 2; ++c32) {
                if (dtile && c32 == 1 && w < 2) continue;
                const bf16x8 pf = *reinterpret_cast<const bf16x8*>(
                    &Pw[c16 * 64 + (((c32 * 4 + g) ^ (c16 & 7)) << 3)]);
                #pragma unroll
                for (int dt = 0; dt < 4; ++dt) {
                    const int vrow = dt * 16 + c16;
                    const bf16x8 vf = *reinterpret_cast<const bf16x8*>(
                        &V_lds[vrow * 64 + (((c32 * 4 + g) ^ (vrow & 7)) << 3)]);
                    acc[dt] = MFMA16(pf, vf, acc[dt], 0, 0, 0);
                }
            }
        }

        // ---- epilogue: cross-lane l reduce (deferred), write O ----
        float lt = lp + __shfl_xor(lp, 16);
        lt += __shfl_xor(lt, 32);
        const float inv = 1.f / lt;
        float invr[4];
        #pragma unroll
        for (int r = 0; r < 4; ++r) invr[r] = __shfl(inv, g * 4 + r);

        #pragma unroll
        for (int dt = 0; dt < 4; ++dt) {
            #pragma unroll
            for (int r = 0; r < 4; ++r) {
                const size_t orow =
                    ((size_t)b * S_LEN + q0 + g * 4 + r) * D_MODEL + hd + dt * 16 + c16;
                AO[orow] = f2bf(acc[dt][r] * invr[r]);
            }
        }
    }
}

extern "C" void kernel_launch(void* const* d_in, const int* in_sizes, int n_in,
                              void* d_out, int out_size, void* d_ws, size_t ws_size,
                              hipStream_t stream) {
    const float* x  = (const float*)d_in[0];
    // d_in[1] = causal mask: applied structurally — not read.
    const float* Wq = (const float*)d_in[2];
    const float* bq = (const float*)d_in[3];
    const float* Wk = (const float*)d_in[4];
    const float* bk = (const float*)d_in[5];
    const float* Wv = (const float*)d_in[6];
    const float* bv = (const float*)d_in[7];
    const float* Wo = (const float*)d_in[8];
    const float* bo = (const float*)d_in[9];
    float* out = (float*)d_out;

    const int M = BATCH * S_LEN;              // 8192
    const size_t tsz = (size_t)M * D_MODEL;
    const size_t wsz = (size_t)D_MODEL * D_MODEL;

    u16* xb  = (u16*)d_ws;
    u16* Qb  = xb + tsz;
    u16* Kb  = Qb + tsz;
    u16* Vb  = Kb + tsz;
    u16* VT  = Vb + tsz;
    u16* WTq = VT + tsz;
    u16* WTk = WTq + wsz;
    u16* WTv = WTk + wsz;
    u16* WTo = WTv + wsz;
    u16* AO  = Vb;             // Vb dead after transpose_v

    convert_x<<<(int)(tsz / (256 * 8)), 256, 0, stream>>>(x, xb);
    transpose_w<<<dim3(16, 16, 4), 256, 0, stream>>>(
        Wq, Wk, Wv, Wo, WTq, WTk, WTv, WTo);

    gemm_qkv<<<dim3(8, 64, 3), 256, 0, stream>>>(
        xb, WTq, WTk, WTv, bq, bk, bv, Qb, Kb, Vb);

    transpose_v<<<2048, 256, 0, stream>>>(Vb, VT);
    flash_attn<<<1024, 256, 0, stream>>>(Qb, Kb, VT, AO);

    gemm_out<<<dim3(8, 64), 256, 0, stream>>>(AO, WTo, bo, out);
}

// Round 6
// 200.455 us; speedup vs baseline: 20.5209x; 1.0293x over previous
//
#include <hip/hip_runtime.h>
#include <hip/hip_bf16.h>

#define D_MODEL 1024
#define NUM_HEADS 16
#define D_K 64
#define S_LEN 2048
#define BATCH 4

typedef unsigned short u16;
typedef __attribute__((ext_vector_type(8))) short bf16x8;
typedef __attribute__((ext_vector_type(4))) float f32x4;

#define MFMA16 __builtin_amdgcn_mfma_f32_16x16x32_bf16

// fold attn scale + ln2 conversion into the Q projection: 0.125 * log2(e)
#define Q_SCALE 0.18033688011112042f

__device__ __forceinline__ float bf2f(u16 u) {
    union { unsigned int i; float f; } v; v.i = ((unsigned int)u) << 16; return v.f;
}
__device__ __forceinline__ u16 f2bf(float f) {
    union { unsigned int i; float f; } v; v.f = f;
    unsigned int x = v.i;
    return (u16)((x + 0x7FFFu + ((x >> 16) & 1u)) >> 16); // round-nearest-even
}
// packed f32x2 -> bf16x2 (RNE), single HW op
__device__ __forceinline__ unsigned int cvtpk(float lo, float hi) {
    unsigned int r;
    asm("v_cvt_pk_bf16_f32 %0, %1, %2" : "=v"(r) : "v"(lo), "v"(hi));
    return r;
}

__device__ __forceinline__ void gload16(const u16* g, u16* l) {
    __builtin_amdgcn_global_load_lds(
        (const __attribute__((address_space(1))) unsigned int*)g,
        (__attribute__((address_space(3))) unsigned int*)l, 16, 0, 0);
}

// ---------------- prep: x fp32 -> bf16 ----------------
__global__ __launch_bounds__(256) void convert_x(
    const float* __restrict__ x, u16* __restrict__ xb)
{
    const size_t i = ((size_t)blockIdx.x * 256 + threadIdx.x) * 8;
    float4 a = *reinterpret_cast<const float4*>(x + i);
    float4 b = *reinterpret_cast<const float4*>(x + i + 4);
    bf16x8 o;
    o[0] = (short)f2bf(a.x); o[1] = (short)f2bf(a.y);
    o[2] = (short)f2bf(a.z); o[3] = (short)f2bf(a.w);
    o[4] = (short)f2bf(b.x); o[5] = (short)f2bf(b.y);
    o[6] = (short)f2bf(b.z); o[7] = (short)f2bf(b.w);
    *reinterpret_cast<bf16x8*>(xb + i) = o;
}

// ---------------- prep: W[k][n] fp32 -> WT[n][k] bf16 (4 matrices) ----------------
__global__ __launch_bounds__(256) void transpose_w(
    const float* __restrict__ W0, const float* __restrict__ W1,
    const float* __restrict__ W2, const float* __restrict__ W3,
    u16* __restrict__ T0, u16* __restrict__ T1,
    u16* __restrict__ T2, u16* __restrict__ T3)
{
    const float* W; u16* T;
    switch (blockIdx.z & 3) {
        case 0:  W = W0; T = T0; break;
        case 1:  W = W1; T = T1; break;
        case 2:  W = W2; T = T2; break;
        default: W = W3; T = T3; break;
    }
    __shared__ u16 S[64][72];
    const int tid = threadIdx.x;
    const int k0 = blockIdx.y * 64, n0 = blockIdx.x * 64;

    const int k = tid >> 2, nb = (tid & 3) * 16;
    #pragma unroll
    for (int c = 0; c < 4; ++c) {
        float4 v = *reinterpret_cast<const float4*>(
            W + (size_t)(k0 + k) * D_MODEL + n0 + nb + c * 4);
        S[nb + c * 4 + 0][k] = f2bf(v.x);
        S[nb + c * 4 + 1][k] = f2bf(v.y);
        S[nb + c * 4 + 2][k] = f2bf(v.z);
        S[nb + c * 4 + 3][k] = f2bf(v.w);
    }
    __syncthreads();
    const int n = tid >> 2, kb = (tid & 3) * 16;
    #pragma unroll
    for (int c = 0; c < 2; ++c) {
        bf16x8 o;
        #pragma unroll
        for (int e = 0; e < 8; ++e) o[e] = (short)S[n][kb + c * 8 + e];
        *reinterpret_cast<bf16x8*>(T + (size_t)(n0 + n) * D_MODEL + k0 + kb + c * 8) = o;
    }
}

// ---------------- MFMA GEMM: C = A[8192,1024] @ BT[1024,1024]^T + bias, then *oscale ----------------
template <typename TC>
__device__ __forceinline__ void gemm_body(
    const u16* __restrict__ A, const u16* __restrict__ BT,
    const float* __restrict__ bias, TC* __restrict__ C,
    u16* Al, u16* Bl, float oscale)
{
    const int tid = threadIdx.x;
    const int w = tid >> 6, lane = tid & 63;
    const int g = lane >> 4, c16 = lane & 15;
    const int wr = w >> 1, wc = w & 1;
    const int m0 = blockIdx.y * 128, n0 = blockIdx.x * 128;

    int rS[4], uS[4];
    #pragma unroll
    for (int i = 0; i < 4; ++i) {
        const int p = i * 256 + tid;
        rS[i] = p >> 3;
        uS[i] = ((p & 7) ^ (rS[i] & 7)) * 8;
    }

    f32x4 acc[4][4];
    #pragma unroll
    for (int mi = 0; mi < 4; ++mi)
        #pragma unroll
        for (int ni = 0; ni < 4; ++ni) acc[mi][ni] = (f32x4){0.f, 0.f, 0.f, 0.f};

    for (int k0 = 0; k0 < D_MODEL; k0 += 64) {
        #pragma unroll
        for (int i = 0; i < 4; ++i) {
            gload16(A + (size_t)(m0 + rS[i]) * D_MODEL + k0 + uS[i],
                    Al + (size_t)(i * 256 + w * 64) * 8);
            gload16(BT + (size_t)(n0 + rS[i]) * D_MODEL + k0 + uS[i],
                    Bl + (size_t)(i * 256 + w * 64) * 8);
        }
        __syncthreads();

        #pragma unroll
        for (int s = 0; s < 2; ++s) {
            bf16x8 af[4], bfr[4];
            #pragma unroll
            for (int mi = 0; mi < 4; ++mi) {
                const int r = wr * 64 + mi * 16 + c16;
                af[mi] = *reinterpret_cast<const bf16x8*>(
                    &Al[((r << 3) + ((s * 4 + g) ^ (r & 7))) * 8]);
            }
            #pragma unroll
            for (int ni = 0; ni < 4; ++ni) {
                const int r = wc * 64 + ni * 16 + c16;
                bfr[ni] = *reinterpret_cast<const bf16x8*>(
                    &Bl[((r << 3) + ((s * 4 + g) ^ (r & 7))) * 8]);
            }
            #pragma unroll
            for (int mi = 0; mi < 4; ++mi)
                #pragma unroll
                for (int ni = 0; ni < 4; ++ni)
                    acc[mi][ni] = MFMA16(af[mi], bfr[ni], acc[mi][ni], 0, 0, 0);
        }
        __syncthreads();
    }

    float bc[4];
    #pragma unroll
    for (int ni = 0; ni < 4; ++ni) bc[ni] = bias[n0 + wc * 64 + ni * 16 + c16];

    #pragma unroll
    for (int mi = 0; mi < 4; ++mi) {
        #pragma unroll
        for (int ni = 0; ni < 4; ++ni) {
            const int col = n0 + wc * 64 + ni * 16 + c16;
            #pragma unroll
            for (int r = 0; r < 4; ++r) {
                const int row = m0 + wr * 64 + mi * 16 + g * 4 + r;
                const float v = (acc[mi][ni][r] + bc[ni]) * oscale;
                if constexpr (sizeof(TC) == 4) {
                    C[(size_t)row * D_MODEL + col] = v;
                } else {
                    C[(size_t)row * D_MODEL + col] = f2bf(v);
                }
            }
        }
    }
}

__global__ __launch_bounds__(256) void gemm_qkv(
    const u16* __restrict__ A,
    const u16* __restrict__ BTq, const u16* __restrict__ BTk, const u16* __restrict__ BTv,
    const float* __restrict__ bq, const float* __restrict__ bk, const float* __restrict__ bv,
    u16* __restrict__ Cq, u16* __restrict__ Ck, u16* __restrict__ Cv)
{
    __shared__ u16 Al[128 * 64];
    __shared__ u16 Bl[128 * 64];
    const u16* BT; const float* bias; u16* C; float sc;
    switch (blockIdx.z) {
        case 0:  BT = BTq; bias = bq; C = Cq; sc = Q_SCALE; break;
        case 1:  BT = BTk; bias = bk; C = Ck; sc = 1.f; break;
        default: BT = BTv; bias = bv; C = Cv; sc = 1.f; break;
    }
    gemm_body<u16>(A, BT, bias, C, Al, Bl, sc);
}

__global__ __launch_bounds__(256) void gemm_out(
    const u16* __restrict__ A, const u16* __restrict__ BT,
    const float* __restrict__ bias, float* __restrict__ C)
{
    __shared__ u16 Al[128 * 64];
    __shared__ u16 Bl[128 * 64];
    gemm_body<float>(A, BT, bias, C, Al, Bl, 1.f);
}

// ---------------- V transpose: Vb[b][j][h*64+d] -> VT[bh][d][j] ----------------
__global__ __launch_bounds__(256) void transpose_v(
    const u16* __restrict__ Vb, u16* __restrict__ VT)
{
    __shared__ u16 T[64 * 65];
    const int i  = blockIdx.x;
    const int bh = i >> 5, jt = i & 31;
    const int b  = bh >> 4, h = bh & 15;
    const int j0 = jt * 64, hd = h * 64;
    const int tid = threadIdx.x;

    #pragma unroll
    for (int it = 0; it < 2; ++it) {
        int seg = it * 256 + tid;
        int jr = seg >> 3, d0 = (seg & 7) * 8;
        bf16x8 v = *reinterpret_cast<const bf16x8*>(
            Vb + ((size_t)(b * S_LEN + j0 + jr)) * D_MODEL + hd + d0);
        #pragma unroll
        for (int e = 0; e < 8; ++e) T[jr * 65 + d0 + e] = (u16)v[e];
    }
    __syncthreads();
    #pragma unroll
    for (int it = 0; it < 2; ++it) {
        int seg = it * 256 + tid;
        int d = seg >> 3, uj = (seg & 7) * 8;
        bf16x8 o;
        #pragma unroll
        for (int e = 0; e < 8; ++e) o[e] = (short)T[(uj + e) * 65 + d];
        *reinterpret_cast<bf16x8*>(
            VT + ((size_t)bh * 64 + d) * S_LEN + j0 + uj) = o;
    }
}

// ---------------- MFMA flash attention v2 ----------------
// 1024 blocks x 512 threads (8 waves). Block i: xcd=i&7, bh=(i>>3)&7 + xcd*8, p=i>>6.
// Waves 0-3 own q-tile p (16 rows each); waves 4-7 own q-tile 31-p. K/V staged ONCE
// per jt and shared by both q-tiles. p ascending in dispatch order = longest first (LPT).
// Scores in log2 domain (Q pre-scaled by 0.125*log2e).
__global__ __launch_bounds__(512, 4) void flash_attn(
    const u16* __restrict__ Qb, const u16* __restrict__ Kb,
    const u16* __restrict__ VT, u16* __restrict__ AO)
{
    __shared__ u16 K_lds[64 * 64];       // [key j][d], XOR-swizzled 16B units
    __shared__ u16 V_lds[64 * 64];       // [d][key j], XOR-swizzled
    __shared__ u16 P_lds[8 * 16 * 64];   // per-wave [q][j], XOR-swizzled

    const int i  = blockIdx.x;
    const int bh = (i & 7) * 8 + ((i >> 3) & 7);
    const int p  = i >> 6;               // 0..15
    const int b  = bh >> 4, h = bh & 15, hd = h * 64;

    const int tid = threadIdx.x;
    const int w = tid >> 6, lane = tid & 63;
    const int wq = w & 3;                // 16-row slice within the wave-group's q-tile
    const int g = lane >> 4, c16 = lane & 15;

    const int qt = (w < 4) ? p : (31 - p);
    const int q0 = qt * 64 + wq * 16;

    const size_t kbase  = (size_t)b * S_LEN * D_MODEL + hd;
    const size_t vtbase = (size_t)bh * 64 * S_LEN;
    u16* Pw = &P_lds[w * 1024];

    const f32x4 ZERO = {0.f, 0.f, 0.f, 0.f};
    const f32x4 NEGI = {-1e30f, -1e30f, -1e30f, -1e30f};

    // staging coords: unit = tid (K) and tid (V); row r=tid>>3, logical 16B unit (tid&7)^(r&7)
    const int rK = tid >> 3;
    const int uK = ((tid & 7) ^ (rK & 7)) * 8;

    const size_t qrow = ((size_t)b * S_LEN + q0 + c16) * D_MODEL + hd;
    const bf16x8 qf0 = *reinterpret_cast<const bf16x8*>(Qb + qrow + g * 8);
    const bf16x8 qf1 = *reinterpret_cast<const bf16x8*>(Qb + qrow + 32 + g * 8);

    f32x4 acc[4];
    #pragma unroll
    for (int dt = 0; dt < 4; ++dt) acc[dt] = ZERO;
    float m = -1e30f, lp = 0.f;          // per-lane: row q=c16; lp = partial l over lane's j-cols

    const int nt = 32 - p;               // tiles for the longer (w>=4) group
    for (int jt = 0; jt < nt; ++jt) {
        const int j0 = jt * 64;

        __syncthreads();
        gload16(Kb + kbase + (size_t)(j0 + rK) * D_MODEL + uK, K_lds + (size_t)tid * 8);
        gload16(VT + vtbase + (size_t)rK * S_LEN + j0 + uK,    V_lds + (size_t)tid * 8);
        __syncthreads();

        if (jt > qt) continue;           // wave-uniform: this q-tile is done (still barriers above)
        const bool dtile = (jt == qt);

        // ---- QK^T swapped: st[kt][r] = S[q=c16][j = kt*16 + g*4 + r] (log2 domain) ----
        f32x4 st[4];
        #pragma unroll
        for (int kt = 0; kt < 4; ++kt) {
            if (dtile && kt > wq) { st[kt] = NEGI; continue; }
            const int row = kt * 16 + c16;
            const bf16x8 kf0 = *reinterpret_cast<const bf16x8*>(
                &K_lds[row * 64 + ((g ^ (row & 7)) << 3)]);
            const bf16x8 kf1 = *reinterpret_cast<const bf16x8*>(
                &K_lds[row * 64 + (((4 + g) ^ (row & 7)) << 3)]);
            f32x4 t = MFMA16(kf0, qf0, ZERO, 0, 0, 0);
            t = MFMA16(kf1, qf1, t, 0, 0, 0);
            if (dtile && kt == wq) {
                #pragma unroll
                for (int r = 0; r < 4; ++r)
                    if (g * 4 + r > c16) t[r] = -1e30f;
            }
            st[kt] = t;
        }

        // ---- in-lane row max + 2 shfl ----
        float mx = st[0][0];
        #pragma unroll
        for (int kt = 0; kt < 4; ++kt)
            #pragma unroll
            for (int r = 0; r < 4; ++r) mx = fmaxf(mx, st[kt][r]);
        mx = fmaxf(mx, __shfl_xor(mx, 16));
        mx = fmaxf(mx, __shfl_xor(mx, 32));

        // ---- defer-max rescale (rare) ----
        if (__any(mx > m + 11.5f)) {
            const float mn = fmaxf(m, mx);
            const float co = __builtin_amdgcn_exp2f(m - mn);
            lp *= co;
            m = mn;
            float cor[4];
            #pragma unroll
            for (int r = 0; r < 4; ++r) cor[r] = __shfl(co, g * 4 + r);
            #pragma unroll
            for (int dt = 0; dt < 4; ++dt)
                #pragma unroll
                for (int r = 0; r < 4; ++r) acc[dt][r] *= cor[r];
        }

        // ---- p = exp2(s - m); l partial in-lane; P -> LDS via cvt_pk + b64 ----
        float tsum = 0.f;
        #pragma unroll
        for (int kt = 0; kt < 4; ++kt) {
            const float p0 = __builtin_amdgcn_exp2f(st[kt][0] - m);
            const float p1 = __builtin_amdgcn_exp2f(st[kt][1] - m);
            const float p2 = __builtin_amdgcn_exp2f(st[kt][2] - m);
            const float p3 = __builtin_amdgcn_exp2f(st[kt][3] - m);
            tsum += (p0 + p1) + (p2 + p3);
            uint2 pw;
            pw.x = cvtpk(p0, p1);
            pw.y = cvtpk(p2, p3);
            const int u = kt * 2 + (g >> 1);
            *reinterpret_cast<uint2*>(
                &Pw[c16 * 64 + ((u ^ (c16 & 7)) << 3) + (g & 1) * 4]) = pw;
        }
        lp += tsum;

        // ---- PV: acc[dt] += P[16x32] * V[32x16] ----
        #pragma unroll
        for (int c32 = 0; c32 < 2; ++c32) {
            if (dtile && c32 == 1 && wq < 2) continue;
            const bf16x8 pf = *reinterpret_cast<const bf16x8*>(
                &Pw[c16 * 64 + (((c32 * 4 + g) ^ (c16 & 7)) << 3)]);
            #pragma unroll
            for (int dt = 0; dt < 4; ++dt) {
                const int vrow = dt * 16 + c16;
                const bf16x8 vf = *reinterpret_cast<const bf16x8*>(
                    &V_lds[vrow * 64 + (((c32 * 4 + g) ^ (vrow & 7)) << 3)]);
                acc[dt] = MFMA16(pf, vf, acc[dt], 0, 0, 0);
            }
        }
    }

    // ---- epilogue: cross-lane l reduce (deferred), write O ----
    float lt = lp + __shfl_xor(lp, 16);
    lt += __shfl_xor(lt, 32);
    const float inv = 1.f / lt;
    float invr[4];
    #pragma unroll
    for (int r = 0; r < 4; ++r) invr[r] = __shfl(inv, g * 4 + r);

    #pragma unroll
    for (int dt = 0; dt < 4; ++dt) {
        #pragma unroll
        for (int r = 0; r < 4; ++r) {
            const size_t orow =
                ((size_t)b * S_LEN + q0 + g * 4 + r) * D_MODEL + hd + dt * 16 + c16;
            AO[orow] = f2bf(acc[dt][r] * invr[r]);
        }
    }
}

extern "C" void kernel_launch(void* const* d_in, const int* in_sizes, int n_in,
                              void* d_out, int out_size, void* d_ws, size_t ws_size,
                              hipStream_t stream) {
    const float* x  = (const float*)d_in[0];
    // d_in[1] = causal mask: applied structurally — not read.
    const float* Wq = (const float*)d_in[2];
    const float* bq = (const float*)d_in[3];
    const float* Wk = (const float*)d_in[4];
    const float* bk = (const float*)d_in[5];
    const float* Wv = (const float*)d_in[6];
    const float* bv = (const float*)d_in[7];
    const float* Wo = (const float*)d_in[8];
    const float* bo = (const float*)d_in[9];
    float* out = (float*)d_out;

    const int M = BATCH * S_LEN;              // 8192
    const size_t tsz = (size_t)M * D_MODEL;
    const size_t wsz = (size_t)D_MODEL * D_MODEL;

    u16* xb  = (u16*)d_ws;
    u16* Qb  = xb + tsz;
    u16* Kb  = Qb + tsz;
    u16* Vb  = Kb + tsz;
    u16* VT  = Vb + tsz;
    u16* WTq = VT + tsz;
    u16* WTk = WTq + wsz;
    u16* WTv = WTk + wsz;
    u16* WTo = WTv + wsz;
    u16* AO  = Vb;             // Vb dead after transpose_v

    convert_x<<<(int)(tsz / (256 * 8)), 256, 0, stream>>>(x, xb);
    transpose_w<<<dim3(16, 16, 4), 256, 0, stream>>>(
        Wq, Wk, Wv, Wo, WTq, WTk, WTv, WTo);

    gemm_qkv<<<dim3(8, 64, 3), 256, 0, stream>>>(
        xb, WTq, WTk, WTv, bq, bk, bv, Qb, Kb, Vb);

    transpose_v<<<2048, 256, 0, stream>>>(Vb, VT);
    flash_attn<<<1024, 512, 0, stream>>>(Qb, Kb, VT, AO);

    gemm_out<<<dim3(8, 64), 256, 0, stream>>>(AO, WTo, bo, out);
}